// Round 1
// baseline (92.966 us; speedup 1.0000x reference)
//
#include <hip/hip_runtime.h>
#include <cstdint>
#include <cstddef>

constexpr int NB   = 16;     // B
constexpr int NC   = 512;    // C
constexpr int ND   = 256;    // D
constexpr int NK   = 32;     // K
constexpr int ROWS = 32;     // rows per block
constexpr int NROW = NB * NC;           // 8192
constexpr int NBLK = NROW / ROWS;       // 256

__global__ __launch_bounds__(512, 2)
void stk_fused(const float* __restrict__ h,
               const int*   __restrict__ topk_idx,
               const float* __restrict__ topk_scores,
               const float* __restrict__ vW, const float* __restrict__ vb,
               const float* __restrict__ oW, const float* __restrict__ ob,
               const float* __restrict__ gW, const float* __restrict__ gb,
               float* __restrict__ out)
{
    __shared__ float s_attn[ROWS][NK];
    __shared__ int   s_idx [ROWS][NK];
    __shared__ float s_wsum[ROWS][ND];
    __shared__ float s_h   [ROWS][ND];
    __shared__ float s_agg [ROWS][ND];

    const int t  = threadIdx.x;
    const int m0 = blockIdx.x * ROWS;                 // first flat row (b*C + c)
    const size_t hb = (size_t)(m0 >> 9) * NC * ND;    // batch base in h (C=512)

    // ---------------- phase 1: softmax over K for all 32 rows ----------------
    {
        const int k  = t & 31;
        const int r0 = t >> 5;                        // 0..15
        #pragma unroll
        for (int half = 0; half < 2; ++half) {
            const int r = r0 + (half << 4);
            const size_t off = (size_t)(m0 + r) * NK + k;
            const float s = topk_scores[off];
            const int  id = topk_idx[off];
            float m = s;
            #pragma unroll
            for (int msk = 16; msk >= 1; msk >>= 1)
                m = fmaxf(m, __shfl_xor(m, msk));
            const float p = __expf(s - m);
            float Z = p;
            #pragma unroll
            for (int msk = 16; msk >= 1; msk >>= 1)
                Z += __shfl_xor(Z, msk);
            s_attn[r][k] = p / Z;
            s_idx [r][k] = id;
        }
    }
    __syncthreads();

    // thread -> (columns d and d+128, rows rb..rb+7)
    const int d  = t & 127;
    const int rb = (t >> 7) * 8;                      // 0,8,16,24

    // ------------- phase 2: stage h rows + gather-weighted-sum ---------------
    #pragma unroll
    for (int i = 0; i < 8; ++i) {
        const int r = rb + i;
        const size_t ro = (size_t)(m0 + r) * ND;
        s_h[r][d]       = h[ro + d];
        s_h[r][d + 128] = h[ro + d + 128];
    }
    #pragma unroll 1
    for (int i = 0; i < 8; ++i) {
        const int r = rb + i;
        float a0 = 0.f, a1 = 0.f;
        #pragma unroll 8
        for (int k = 0; k < NK; ++k) {
            const float w  = s_attn[r][k];
            const size_t nb = hb + (size_t)s_idx[r][k] * ND;
            a0 = fmaf(w, h[nb + d],       a0);
            a1 = fmaf(w, h[nb + d + 128], a1);
        }
        s_wsum[r][d]       = a0;
        s_wsum[r][d + 128] = a1;
    }
    __syncthreads();

    // ---------------- phase 3: agg = wsum @ vW + vb --------------------------
    float agg0[8], agg1[8];
    {
        const float b0 = vb[d], b1 = vb[d + 128];
        #pragma unroll
        for (int i = 0; i < 8; ++i) { agg0[i] = b0; agg1[i] = b1; }
        for (int e0 = 0; e0 < ND; e0 += 4) {
            float w0[4], w1[4];
            #pragma unroll
            for (int j = 0; j < 4; ++j) {
                w0[j] = vW[(size_t)(e0 + j) * ND + d];
                w1[j] = vW[(size_t)(e0 + j) * ND + d + 128];
            }
            #pragma unroll
            for (int i = 0; i < 8; ++i) {
                const float4 a = *reinterpret_cast<const float4*>(&s_wsum[rb + i][e0]);
                agg0[i] = fmaf(a.x, w0[0], agg0[i]); agg1[i] = fmaf(a.x, w1[0], agg1[i]);
                agg0[i] = fmaf(a.y, w0[1], agg0[i]); agg1[i] = fmaf(a.y, w1[1], agg1[i]);
                agg0[i] = fmaf(a.z, w0[2], agg0[i]); agg1[i] = fmaf(a.z, w1[2], agg1[i]);
                agg0[i] = fmaf(a.w, w0[3], agg0[i]); agg1[i] = fmaf(a.w, w1[3], agg1[i]);
            }
        }
        #pragma unroll
        for (int i = 0; i < 8; ++i) {
            s_agg[rb + i][d]       = agg0[i];
            s_agg[rb + i][d + 128] = agg1[i];
        }
    }
    __syncthreads();

    // ------- phase 4: o = agg@oW + ob ; g = [h,agg]@gW + gb ; out = sig(g)*o -
    float o0[8], o1[8], g0[8], g1[8];
    {
        const float obb0 = ob[d], obb1 = ob[d + 128];
        const float gbb0 = gb[d], gbb1 = gb[d + 128];
        #pragma unroll
        for (int i = 0; i < 8; ++i) { o0[i]=obb0; o1[i]=obb1; g0[i]=gbb0; g1[i]=gbb1; }
        for (int e0 = 0; e0 < ND; e0 += 4) {
            float ow0[4], ow1[4], gh0[4], gh1[4], ga0[4], ga1[4];
            #pragma unroll
            for (int j = 0; j < 4; ++j) {
                const size_t er = (size_t)(e0 + j) * ND;
                ow0[j] = oW[er + d];                    ow1[j] = oW[er + d + 128];
                gh0[j] = gW[er + d];                    gh1[j] = gW[er + d + 128];
                ga0[j] = gW[er + (size_t)ND * ND + d];  ga1[j] = gW[er + (size_t)ND * ND + d + 128];
            }
            #pragma unroll
            for (int i = 0; i < 8; ++i) {
                const float4 a  = *reinterpret_cast<const float4*>(&s_agg[rb + i][e0]);
                const float4 hh = *reinterpret_cast<const float4*>(&s_h  [rb + i][e0]);
                o0[i] = fmaf(a.x, ow0[0], o0[i]); o0[i] = fmaf(a.y, ow0[1], o0[i]);
                o0[i] = fmaf(a.z, ow0[2], o0[i]); o0[i] = fmaf(a.w, ow0[3], o0[i]);
                o1[i] = fmaf(a.x, ow1[0], o1[i]); o1[i] = fmaf(a.y, ow1[1], o1[i]);
                o1[i] = fmaf(a.z, ow1[2], o1[i]); o1[i] = fmaf(a.w, ow1[3], o1[i]);
                g0[i] = fmaf(hh.x, gh0[0], g0[i]); g0[i] = fmaf(hh.y, gh0[1], g0[i]);
                g0[i] = fmaf(hh.z, gh0[2], g0[i]); g0[i] = fmaf(hh.w, gh0[3], g0[i]);
                g1[i] = fmaf(hh.x, gh1[0], g1[i]); g1[i] = fmaf(hh.y, gh1[1], g1[i]);
                g1[i] = fmaf(hh.z, gh1[2], g1[i]); g1[i] = fmaf(hh.w, gh1[3], g1[i]);
                g0[i] = fmaf(a.x, ga0[0], g0[i]); g0[i] = fmaf(a.y, ga0[1], g0[i]);
                g0[i] = fmaf(a.z, ga0[2], g0[i]); g0[i] = fmaf(a.w, ga0[3], g0[i]);
                g1[i] = fmaf(a.x, ga1[0], g1[i]); g1[i] = fmaf(a.y, ga1[1], g1[i]);
                g1[i] = fmaf(a.z, ga1[2], g1[i]); g1[i] = fmaf(a.w, ga1[3], g1[i]);
            }
        }
    }
    #pragma unroll
    for (int i = 0; i < 8; ++i) {
        const size_t ro = (size_t)(m0 + rb + i) * ND;
        const float sg0 = 1.f / (1.f + __expf(-g0[i]));
        const float sg1 = 1.f / (1.f + __expf(-g1[i]));
        out[ro + d]       = sg0 * o0[i];
        out[ro + d + 128] = sg1 * o1[i];
    }
}

extern "C" void kernel_launch(void* const* d_in, const int* in_sizes, int n_in,
                              void* d_out, int out_size, void* d_ws, size_t ws_size,
                              hipStream_t stream) {
    const float* h   = (const float*)d_in[0];
    const int*   idx = (const int*)  d_in[1];   // integer input -> int32 per harness contract
    const float* sc  = (const float*)d_in[2];
    const float* vW  = (const float*)d_in[3];
    const float* vb  = (const float*)d_in[4];
    const float* oW  = (const float*)d_in[5];
    const float* ob  = (const float*)d_in[6];
    const float* gW  = (const float*)d_in[7];
    const float* gb  = (const float*)d_in[8];
    float* out = (float*)d_out;

    stk_fused<<<NBLK, 512, 0, stream>>>(h, idx, sc, vW, vb, oW, ob, gW, gb, out);
}

// Round 2
// 41.613 us; speedup vs baseline: 2.2341x; 2.2341x over previous
//
#include <hip/hip_runtime.h>
#include <hip/hip_bf16.h>
#include <cstdint>
#include <cstddef>

using short8 = __attribute__((ext_vector_type(8))) short;
using f32x4  = __attribute__((ext_vector_type(4))) float;

constexpr int NB = 16, NC = 512, ND = 256, NK = 32;
constexpr int ROWS = 32;
constexpr int NROW = NB * NC;          // 8192
constexpr int NBLK = NROW / ROWS;      // 256
constexpr int LDP  = ND + 8;           // padded LDS row stride (ushort) -> 528 B, 2-way banks (free)

// packed bf16 weight layout in d_ws (element offsets):
//  vW frags: [0, 65536)        fragment fl = nt*8  + ks   (nt 0..15, ks 0..7)
//  oW frags: [65536, 131072)
//  gW frags: [131072, 262144)  fragment fl = nt*16 + ks   (ks 0..15; 0..7 = h-half, 8..15 = agg-half)
// within fragment: elem = (fl_global*64 + lane)*8 + j  == source W[ks*32 + (lane>>4)*8 + j][nt*16 + (lane&15)]
constexpr int PVW = 0;
constexpr int POW = 65536;
constexpr int PGW = 131072;
constexpr size_t WS_NEED = 262144ull * 2;

static __device__ __forceinline__ unsigned short f2bf(float f) {
    __hip_bfloat16 b = __float2bfloat16(f);
    return *reinterpret_cast<unsigned short*>(&b);
}

// ---------------------------------------------------------------------------
// prep: pack vW/oW/gW (f32, row-major [K][N]) into fragment-major bf16
// ---------------------------------------------------------------------------
__global__ __launch_bounds__(256)
void stk_pack(const float* __restrict__ vW, const float* __restrict__ oW,
              const float* __restrict__ gW, unsigned short* __restrict__ ws)
{
    const int tid  = blockIdx.x * 256 + threadIdx.x;   // 32768 threads total
    const int lane = tid & 63;
    const int fl   = tid >> 6;                         // global fragment id 0..511
    const float* src; int nt, ks;
    if (fl < 128)      { src = vW; nt = fl >> 3;         ks = fl & 7;          }
    else if (fl < 256) { src = oW; nt = (fl - 128) >> 3; ks = (fl - 128) & 7;  }
    else               { src = gW; nt = (fl - 256) >> 4; ks = (fl - 256) & 15; }
    const int col = nt * 16 + (lane & 15);
    const int k0  = ks * 32 + (lane >> 4) * 8;
    short8 v;
    #pragma unroll
    for (int j = 0; j < 8; ++j)
        v[j] = (short)f2bf(src[(size_t)(k0 + j) * ND + col]);
    *reinterpret_cast<short8*>(&ws[(size_t)tid * 8]) = v;   // dest = tid*8 for all three mats
}

// ---------------------------------------------------------------------------
// main fused kernel (MFMA path)
// ---------------------------------------------------------------------------
__global__ __launch_bounds__(512, 2)
void stk_mfma(const float* __restrict__ h,
              const int*   __restrict__ topk_idx,
              const float* __restrict__ topk_scores,
              const float* __restrict__ vb, const float* __restrict__ ob,
              const float* __restrict__ gb,
              const unsigned short* __restrict__ wsb,
              float* __restrict__ out)
{
    __shared__ float          s_attn[ROWS][NK];
    __shared__ int            s_idx [ROWS][NK];
    __shared__ __align__(16) unsigned short s_w [ROWS][LDP];   // wsum bf16
    __shared__ __align__(16) unsigned short s_hb[ROWS][LDP];   // h    bf16
    __shared__ __align__(16) unsigned short s_ab[ROWS][LDP];   // agg  bf16

    const int t  = threadIdx.x;
    const int m0 = blockIdx.x * ROWS;
    const size_t hb0 = (size_t)(m0 >> 9) * NC * ND;   // batch base (C=512)

    // ------------- phase 1: softmax over K (width-32 butterflies) -----------
    {
        const int k  = t & 31;
        const int r0 = t >> 5;                        // 0..15
        #pragma unroll
        for (int half = 0; half < 2; ++half) {
            const int r = r0 + (half << 4);
            const size_t off = (size_t)(m0 + r) * NK + k;
            const float s = topk_scores[off];
            const int  id = topk_idx[off];
            float m = s;
            #pragma unroll
            for (int msk = 16; msk >= 1; msk >>= 1)
                m = fmaxf(m, __shfl_xor(m, msk));
            const float p = __expf(s - m);
            float Z = p;
            #pragma unroll
            for (int msk = 16; msk >= 1; msk >>= 1)
                Z += __shfl_xor(Z, msk);
            s_attn[r][k] = p / Z;
            s_idx [r][k] = id;
        }
    }
    __syncthreads();

    // ------------- phase 2: stage h (bf16) + gather-weighted-sum ------------
    {
        const int d  = t & 127;
        const int rb = (t >> 7) * 8;
        #pragma unroll
        for (int i = 0; i < 8; ++i) {
            const int r = rb + i;
            const size_t ro = (size_t)(m0 + r) * ND;
            s_hb[r][d]       = f2bf(h[ro + d]);
            s_hb[r][d + 128] = f2bf(h[ro + d + 128]);
        }
        #pragma unroll 1
        for (int i = 0; i < 8; ++i) {
            const int r = rb + i;
            float a0 = 0.f, a1 = 0.f;
            #pragma unroll 8
            for (int k = 0; k < NK; ++k) {
                const float w  = s_attn[r][k];
                const size_t nb = hb0 + (size_t)s_idx[r][k] * ND;
                a0 = fmaf(w, h[nb + d],       a0);
                a1 = fmaf(w, h[nb + d + 128], a1);
            }
            s_w[r][d]       = f2bf(a0);
            s_w[r][d + 128] = f2bf(a1);
        }
    }
    __syncthreads();

    const int w    = t >> 6;        // wave 0..7
    const int lane = t & 63;
    const int lr   = lane & 15;     // frag row/col
    const int lg   = lane >> 4;     // frag k-group
    const int n0   = 2 * w;         // this wave's first N-tile

    // ------------- phase 3: agg = wsum @ vW + vb (MFMA) ---------------------
    {
        f32x4 acc[2][2];
        #pragma unroll
        for (int n = 0; n < 2; ++n) {
            const float bv = vb[(n0 + n) * 16 + lr];
            #pragma unroll
            for (int m = 0; m < 2; ++m)
                acc[m][n] = f32x4{bv, bv, bv, bv};
        }
        #pragma unroll
        for (int ks = 0; ks < 8; ++ks) {
            const int kb = ks * 32 + lg * 8;
            const short8 a0 = *reinterpret_cast<const short8*>(&s_w[lr][kb]);
            const short8 a1 = *reinterpret_cast<const short8*>(&s_w[16 + lr][kb]);
            #pragma unroll
            for (int n = 0; n < 2; ++n) {
                const short8 b = *reinterpret_cast<const short8*>(
                    &wsb[(size_t)(PVW + (((n0 + n) * 8 + ks) * 64 + lane) * 8)]);
                acc[0][n] = __builtin_amdgcn_mfma_f32_16x16x32_bf16(a0, b, acc[0][n], 0, 0, 0);
                acc[1][n] = __builtin_amdgcn_mfma_f32_16x16x32_bf16(a1, b, acc[1][n], 0, 0, 0);
            }
        }
        #pragma unroll
        for (int m = 0; m < 2; ++m)
            #pragma unroll
            for (int n = 0; n < 2; ++n) {
                const int col = (n0 + n) * 16 + lr;
                #pragma unroll
                for (int r = 0; r < 4; ++r)
                    s_ab[m * 16 + 4 * lg + r][col] = f2bf(acc[m][n][r]);
            }
    }
    __syncthreads();

    // ------ phase 4: o = agg@oW + ob ; g = h@gW_h + agg@gW_a + gb (MFMA) ----
    {
        f32x4 ao[2][2], ag[2][2];
        #pragma unroll
        for (int n = 0; n < 2; ++n) {
            const float bo = ob[(n0 + n) * 16 + lr];
            const float bg = gb[(n0 + n) * 16 + lr];
            #pragma unroll
            for (int m = 0; m < 2; ++m) {
                ao[m][n] = f32x4{bo, bo, bo, bo};
                ag[m][n] = f32x4{bg, bg, bg, bg};
            }
        }
        #pragma unroll
        for (int ks = 0; ks < 8; ++ks) {
            const int kb = ks * 32 + lg * 8;
            const short8 aa0 = *reinterpret_cast<const short8*>(&s_ab[lr][kb]);
            const short8 aa1 = *reinterpret_cast<const short8*>(&s_ab[16 + lr][kb]);
            const short8 ah0 = *reinterpret_cast<const short8*>(&s_hb[lr][kb]);
            const short8 ah1 = *reinterpret_cast<const short8*>(&s_hb[16 + lr][kb]);
            #pragma unroll
            for (int n = 0; n < 2; ++n) {
                const int nt = n0 + n;
                const short8 b_o  = *reinterpret_cast<const short8*>(
                    &wsb[(size_t)(POW + ((nt * 8 + ks) * 64 + lane) * 8)]);
                const short8 b_g1 = *reinterpret_cast<const short8*>(
                    &wsb[(size_t)(PGW + ((nt * 16 + ks) * 64 + lane) * 8)]);
                const short8 b_g2 = *reinterpret_cast<const short8*>(
                    &wsb[(size_t)(PGW + ((nt * 16 + ks + 8) * 64 + lane) * 8)]);
                ao[0][n] = __builtin_amdgcn_mfma_f32_16x16x32_bf16(aa0, b_o,  ao[0][n], 0, 0, 0);
                ao[1][n] = __builtin_amdgcn_mfma_f32_16x16x32_bf16(aa1, b_o,  ao[1][n], 0, 0, 0);
                ag[0][n] = __builtin_amdgcn_mfma_f32_16x16x32_bf16(ah0, b_g1, ag[0][n], 0, 0, 0);
                ag[1][n] = __builtin_amdgcn_mfma_f32_16x16x32_bf16(ah1, b_g1, ag[1][n], 0, 0, 0);
                ag[0][n] = __builtin_amdgcn_mfma_f32_16x16x32_bf16(aa0, b_g2, ag[0][n], 0, 0, 0);
                ag[1][n] = __builtin_amdgcn_mfma_f32_16x16x32_bf16(aa1, b_g2, ag[1][n], 0, 0, 0);
            }
        }
        #pragma unroll
        for (int m = 0; m < 2; ++m)
            #pragma unroll
            for (int n = 0; n < 2; ++n) {
                const int col = (n0 + n) * 16 + lr;
                #pragma unroll
                for (int r = 0; r < 4; ++r) {
                    const int row = m0 + m * 16 + 4 * lg + r;
                    const float g = 1.f / (1.f + __expf(-ag[m][n][r]));
                    out[(size_t)row * ND + col] = g * ao[m][n][r];
                }
            }
    }
}

// ---------------------------------------------------------------------------
// fallback: proven f32 kernel from R1 (used only if ws_size < WS_NEED)
// ---------------------------------------------------------------------------
__global__ __launch_bounds__(512, 2)
void stk_fused(const float* __restrict__ h,
               const int*   __restrict__ topk_idx,
               const float* __restrict__ topk_scores,
               const float* __restrict__ vW, const float* __restrict__ vb,
               const float* __restrict__ oW, const float* __restrict__ ob,
               const float* __restrict__ gW, const float* __restrict__ gb,
               float* __restrict__ out)
{
    __shared__ float s_attn[ROWS][NK];
    __shared__ int   s_idx [ROWS][NK];
    __shared__ float s_wsum[ROWS][ND];
    __shared__ float s_h   [ROWS][ND];
    __shared__ float s_agg [ROWS][ND];

    const int t  = threadIdx.x;
    const int m0 = blockIdx.x * ROWS;
    const size_t hb = (size_t)(m0 >> 9) * NC * ND;

    {
        const int k  = t & 31;
        const int r0 = t >> 5;
        #pragma unroll
        for (int half = 0; half < 2; ++half) {
            const int r = r0 + (half << 4);
            const size_t off = (size_t)(m0 + r) * NK + k;
            const float s = topk_scores[off];
            const int  id = topk_idx[off];
            float m = s;
            #pragma unroll
            for (int msk = 16; msk >= 1; msk >>= 1) m = fmaxf(m, __shfl_xor(m, msk));
            const float p = __expf(s - m);
            float Z = p;
            #pragma unroll
            for (int msk = 16; msk >= 1; msk >>= 1) Z += __shfl_xor(Z, msk);
            s_attn[r][k] = p / Z;
            s_idx [r][k] = id;
        }
    }
    __syncthreads();

    const int d  = t & 127;
    const int rb = (t >> 7) * 8;

    #pragma unroll
    for (int i = 0; i < 8; ++i) {
        const int r = rb + i;
        const size_t ro = (size_t)(m0 + r) * ND;
        s_h[r][d]       = h[ro + d];
        s_h[r][d + 128] = h[ro + d + 128];
    }
    #pragma unroll 1
    for (int i = 0; i < 8; ++i) {
        const int r = rb + i;
        float a0 = 0.f, a1 = 0.f;
        #pragma unroll 8
        for (int k = 0; k < NK; ++k) {
            const float w  = s_attn[r][k];
            const size_t nb = hb + (size_t)s_idx[r][k] * ND;
            a0 = fmaf(w, h[nb + d],       a0);
            a1 = fmaf(w, h[nb + d + 128], a1);
        }
        s_wsum[r][d]       = a0;
        s_wsum[r][d + 128] = a1;
    }
    __syncthreads();

    float agg0[8], agg1[8];
    {
        const float b0 = vb[d], b1 = vb[d + 128];
        #pragma unroll
        for (int i = 0; i < 8; ++i) { agg0[i] = b0; agg1[i] = b1; }
        for (int e0 = 0; e0 < ND; e0 += 4) {
            float w0[4], w1[4];
            #pragma unroll
            for (int j = 0; j < 4; ++j) {
                w0[j] = vW[(size_t)(e0 + j) * ND + d];
                w1[j] = vW[(size_t)(e0 + j) * ND + d + 128];
            }
            #pragma unroll
            for (int i = 0; i < 8; ++i) {
                const float4 a = *reinterpret_cast<const float4*>(&s_wsum[rb + i][e0]);
                agg0[i] = fmaf(a.x, w0[0], agg0[i]); agg1[i] = fmaf(a.x, w1[0], agg1[i]);
                agg0[i] = fmaf(a.y, w0[1], agg0[i]); agg1[i] = fmaf(a.y, w1[1], agg1[i]);
                agg0[i] = fmaf(a.z, w0[2], agg0[i]); agg1[i] = fmaf(a.z, w1[2], agg1[i]);
                agg0[i] = fmaf(a.w, w0[3], agg0[i]); agg1[i] = fmaf(a.w, w1[3], agg1[i]);
            }
        }
        #pragma unroll
        for (int i = 0; i < 8; ++i) {
            s_agg[rb + i][d]       = agg0[i];
            s_agg[rb + i][d + 128] = agg1[i];
        }
    }
    __syncthreads();

    float o0[8], o1[8], g0[8], g1[8];
    {
        const float obb0 = ob[d], obb1 = ob[d + 128];
        const float gbb0 = gb[d], gbb1 = gb[d + 128];
        #pragma unroll
        for (int i = 0; i < 8; ++i) { o0[i]=obb0; o1[i]=obb1; g0[i]=gbb0; g1[i]=gbb1; }
        for (int e0 = 0; e0 < ND; e0 += 4) {
            float ow0[4], ow1[4], gh0[4], gh1[4], ga0[4], ga1[4];
            #pragma unroll
            for (int j = 0; j < 4; ++j) {
                const size_t er = (size_t)(e0 + j) * ND;
                ow0[j] = oW[er + d];                    ow1[j] = oW[er + d + 128];
                gh0[j] = gW[er + d];                    gh1[j] = gW[er + d + 128];
                ga0[j] = gW[er + (size_t)ND * ND + d];  ga1[j] = gW[er + (size_t)ND * ND + d + 128];
            }
            #pragma unroll
            for (int i = 0; i < 8; ++i) {
                const float4 a  = *reinterpret_cast<const float4*>(&s_agg[rb + i][e0]);
                const float4 hh = *reinterpret_cast<const float4*>(&s_h  [rb + i][e0]);
                o0[i] = fmaf(a.x, ow0[0], o0[i]); o0[i] = fmaf(a.y, ow0[1], o0[i]);
                o0[i] = fmaf(a.z, ow0[2], o0[i]); o0[i] = fmaf(a.w, ow0[3], o0[i]);
                o1[i] = fmaf(a.x, ow1[0], o1[i]); o1[i] = fmaf(a.y, ow1[1], o1[i]);
                o1[i] = fmaf(a.z, ow1[2], o1[i]); o1[i] = fmaf(a.w, ow1[3], o1[i]);
                g0[i] = fmaf(hh.x, gh0[0], g0[i]); g0[i] = fmaf(hh.y, gh0[1], g0[i]);
                g0[i] = fmaf(hh.z, gh0[2], g0[i]); g0[i] = fmaf(hh.w, gh0[3], g0[i]);
                g1[i] = fmaf(hh.x, gh1[0], g1[i]); g1[i] = fmaf(hh.y, gh1[1], g1[i]);
                g1[i] = fmaf(hh.z, gh1[2], g1[i]); g1[i] = fmaf(hh.w, gh1[3], g1[i]);
                g0[i] = fmaf(a.x, ga0[0], g0[i]); g0[i] = fmaf(a.y, ga0[1], g0[i]);
                g0[i] = fmaf(a.z, ga0[2], g0[i]); g0[i] = fmaf(a.w, ga0[3], g0[i]);
                g1[i] = fmaf(a.x, ga1[0], g1[i]); g1[i] = fmaf(a.y, ga1[1], g1[i]);
                g1[i] = fmaf(a.z, ga1[2], g1[i]); g1[i] = fmaf(a.w, ga1[3], g1[i]);
            }
        }
    }
    #pragma unroll
    for (int i = 0; i < 8; ++i) {
        const size_t ro = (size_t)(m0 + rb + i) * ND;
        const float sg0 = 1.f / (1.f + __expf(-g0[i]));
        const float sg1 = 1.f / (1.f + __expf(-g1[i]));
        out[ro + d]       = sg0 * o0[i];
        out[ro + d + 128] = sg1 * o1[i];
    }
}

extern "C" void kernel_launch(void* const* d_in, const int* in_sizes, int n_in,
                              void* d_out, int out_size, void* d_ws, size_t ws_size,
                              hipStream_t stream) {
    const float* h   = (const float*)d_in[0];
    const int*   idx = (const int*)  d_in[1];
    const float* sc  = (const float*)d_in[2];
    const float* vW  = (const float*)d_in[3];
    const float* vb  = (const float*)d_in[4];
    const float* oW  = (const float*)d_in[5];
    const float* ob  = (const float*)d_in[6];
    const float* gW  = (const float*)d_in[7];
    const float* gb  = (const float*)d_in[8];
    float* out = (float*)d_out;

    if (ws_size >= WS_NEED) {
        unsigned short* wsb = (unsigned short*)d_ws;
        stk_pack<<<128, 256, 0, stream>>>(vW, oW, gW, wsb);
        stk_mfma<<<NBLK, 512, 0, stream>>>(h, idx, sc, vb, ob, gb, wsb, out);
    } else {
        stk_fused<<<NBLK, 512, 0, stream>>>(h, idx, sc, vW, vb, oW, ob, gW, gb, out);
    }
}